// Round 16
// baseline (87.648 us; speedup 1.0000x reference)
//
#include <hip/hip_runtime.h>
#include <math.h>
#include <stdint.h>

#define NTRAIN 16384
#define DIM 64
#define ODIM 8
#define BATCH 8192
#define LOG2E 1.4426950408889634f

typedef float f32x4 __attribute__((ext_vector_type(4)));
typedef _Float16 f16x8 __attribute__((ext_vector_type(8)));
typedef short short8 __attribute__((ext_vector_type(8)));
typedef unsigned short u16;

// float -> fp16 bits, RNE
static __device__ __forceinline__ u16 f2h(float f) {
  return __builtin_bit_cast(u16, (_Float16)f);
}
static __device__ __forceinline__ float h2f(u16 h) {
  return (float)__builtin_bit_cast(_Float16, h);
}
// float -> bf16 bits, RNE
static __device__ __forceinline__ u16 f2bf(float f) {
  unsigned u = __builtin_bit_cast(unsigned, f);
  u += 0x7FFFu + ((u >> 16) & 1u);
  return (u16)(u >> 16);
}

static __device__ __forceinline__ f32x4 mfma_h32(f16x8 a, f16x8 b, f32x4 c) {
  return __builtin_amdgcn_mfma_f32_16x16x32_f16(a, b, c, 0, 0, 0);
}
static __device__ __forceinline__ f32x4 mfma_bf32(short8 a, short8 b, f32x4 c) {
  return __builtin_amdgcn_mfma_f32_16x16x32_bf16(a, b, c, 0, 0, 0);
}
// 2^(-x)
static __device__ __forceinline__ float ex2n(float x) {
  float r;
  asm("v_exp_f32 %0, -%1" : "=v"(r) : "v"(x));
  return r;
}
// pack two f32 -> one u32 of 2 bf16 (keeps fp32 exponent range!)
static __device__ __forceinline__ unsigned pkbf(float a, float b) {
  unsigned d;
  asm("v_cvt_pk_bf16_f32 %0, %1, %2" : "=v"(d) : "v"(a), "v"(b));
  return d;
}

// ---------------------------------------------------------------------------
// k_frag:
//  X: per 16-n tile, 3 fp16 A-fragments for 16x16x32 f16 S-GEMM:
//   f=0,1 : 2*gamma_n^2 * x[n][k], lane l -> row n=tile*16+(l&15),
//           k = f*32 + (l>>4)*8 + j
//   f=2   : norm kstep (lane group 0): [gx2_h, gx2_l, g2_h, g2_h, g2_l, 0..]
//  V: per 32-n PAIR tile, bf16 B-fragment for 16x16x32 bf16 PV:
//   lane l -> col=l&15, k=(l>>4)*8+j; k maps to n = t*32 + (j<4 ? lg*4+j
//   : 16+lg*4+j-4)  (slab A in k-slots 0..3, slab B in 4..7). V=[1|y|0pad].
// ---------------------------------------------------------------------------
__global__ __launch_bounds__(256) void k_frag(
    const float* __restrict__ xt, const float* __restrict__ yt,
    const float* __restrict__ beta,
    u16* __restrict__ xf, u16* __restrict__ yv) {
  int tid = blockIdx.x * 256 + threadIdx.x;

  if (tid < (NTRAIN / 16) * 3 * 64) {
    int fg = tid >> 6, lane = tid & 63;
    int tile = fg / 3, f = fg % 3;
    int lr = lane & 15, lg = lane >> 4;
    int n = tile * 16 + lr;
    uint4 u = {0, 0, 0, 0};
    if (f == 2) {
      if (lg == 0) {
        float g = beta[n] * LOG2E;
        float g2v = g * g;
        const float4* r4 = (const float4*)(xt + (size_t)n * DIM);
        float s0 = 0.f, s1 = 0.f, s2 = 0.f, s3 = 0.f;
#pragma unroll
        for (int q = 0; q < DIM / 4; ++q) {
          float4 v = r4[q];
          s0 = fmaf(v.x, v.x, s0); s1 = fmaf(v.y, v.y, s1);
          s2 = fmaf(v.z, v.z, s2); s3 = fmaf(v.w, v.w, s3);
        }
        float gx2v = g2v * ((s0 + s1) + (s2 + s3));
        u16 xh = f2h(gx2v);
        u16 xl = f2h(gx2v - h2f(xh));
        u16 gh = f2h(g2v);
        u16 gl = f2h(g2v - h2f(gh));
        u.x = (unsigned)xh | ((unsigned)xl << 16);
        u.y = (unsigned)gh | ((unsigned)gh << 16);
        u.z = (unsigned)gl;
      }
    } else {
      float g = beta[n] * LOG2E;
      float s2g = 2.0f * g * g;
      const float* src = xt + (size_t)n * DIM + f * 32 + lg * 8;
      unsigned e[8];
#pragma unroll
      for (int j = 0; j < 8; ++j) e[j] = f2h(s2g * src[j]);
      u.x = e[0] | (e[1] << 16); u.y = e[2] | (e[3] << 16);
      u.z = e[4] | (e[5] << 16); u.w = e[6] | (e[7] << 16);
    }
    ((uint4*)xf)[(size_t)fg * 64 + lane] = u;
    return;
  }
  tid -= (NTRAIN / 16) * 3 * 64;

  if (tid < (NTRAIN / 32) * 64) {  // V pair fragments (bf16)
    int t = tid >> 6, lane = tid & 63;
    int col = lane & 15, lg = lane >> 4;
    unsigned e[8];
#pragma unroll
    for (int j = 0; j < 8; ++j) {
      int n = t * 32 + ((j < 4) ? (lg * 4 + j) : (16 + lg * 4 + (j - 4)));
      float v = (col == 0) ? 1.0f
                           : ((col < 9) ? yt[(size_t)n * ODIM + (col - 1)] : 0.0f);
      e[j] = f2bf(v);
    }
    uint4 u;
    u.x = e[0] | (e[1] << 16); u.y = e[2] | (e[3] << 16);
    u.z = e[4] | (e[5] << 16); u.w = e[6] | (e[7] << 16);
    ((uint4*)yv)[(size_t)t * 64 + lane] = u;
  }
}

// ---------------------------------------------------------------------------
// Pass 1: 16x16 tiles, high occupancy. fp16 S-GEMM (3 MFMAs incl norm-fold),
// bf16 P (exponent-safe!) -> one 16x16x32 bf16 PV per 2 slabs.
// Barrier-free; register-double-buffered; XCD c-locality swizzle.
// ---------------------------------------------------------------------------
#define LOADX3(X_, nbv)                                                       \
  {                                                                           \
    const size_t fb_ = (size_t)((nbv) >> 4) * 3;                              \
    X_[0] = xf4[(fb_ + 0) * 64 + lane];                                       \
    X_[1] = xf4[(fb_ + 1) * 64 + lane];                                       \
    X_[2] = xf4[(fb_ + 2) * 64 + lane];                                       \
  }

#define SCOMP(X_, U0_, U1_)                                                   \
  {                                                                           \
    f32x4 sA = {0.f, 0.f, 0.f, 0.f};                                          \
    __builtin_amdgcn_s_setprio(1);                                            \
    sA = mfma_h32(__builtin_bit_cast(f16x8, X_[2]), BN, sA);                  \
    sA = mfma_h32(__builtin_bit_cast(f16x8, X_[0]), BH[0], sA);               \
    sA = mfma_h32(__builtin_bit_cast(f16x8, X_[1]), BH[1], sA);               \
    __builtin_amdgcn_s_setprio(0);                                            \
    float w0 = ex2n(__builtin_amdgcn_sqrtf(fabsf(sA[0])));                    \
    float w1 = ex2n(__builtin_amdgcn_sqrtf(fabsf(sA[1])));                    \
    float w2 = ex2n(__builtin_amdgcn_sqrtf(fabsf(sA[2])));                    \
    float w3 = ex2n(__builtin_amdgcn_sqrtf(fabsf(sA[3])));                    \
    U0_ = pkbf(w0, w1);                                                       \
    U1_ = pkbf(w2, w3);                                                       \
  }

__global__ __launch_bounds__(256, 6) void grnn_pass1(
    const u16* __restrict__ xf, const u16* __restrict__ yv,
    const float* __restrict__ batches,
    float* __restrict__ partial, int chunk_n, int nc) {
  const int lane = threadIdx.x & 63;
  const int lr = lane & 15, lg = lane >> 4;

  // XCD c-locality swizzle (bijective for nc==32, grid 4096).
  int mt, c;
  if (nc == 32) {
    const int bid = blockIdx.x;
    const int xcd = bid & 7;
    const int q = bid >> 3;          // 0..511
    c = xcd + 8 * (q & 3);           // 4 c-slices per XCD
    mt = q >> 2;                     // 0..127
  } else {
    mt = blockIdx.x % (BATCH / 64);
    c = blockIdx.x / (BATCH / 64);
  }
  const int mbase = mt * 64 + (threadIdx.x >> 6) * 16;
  const int n0 = c * chunk_n;
  const int npair = chunk_n / 32;    // >= 16

  // Batch B-fragments (fp16): 2 ksteps; b2 via in-wave shfl reduce.
  f16x8 BH[2], BN;
  const int mrow = mbase + lr;
  float ssum = 0.f;
#pragma unroll
  for (int ks = 0; ks < 2; ++ks) {
    const float* src = batches + (size_t)mrow * DIM + ks * 32 + lg * 8;
    float4 v0 = *(const float4*)src;
    float4 v1 = *(const float4*)(src + 4);
    BH[ks][0] = (_Float16)v0.x; BH[ks][1] = (_Float16)v0.y;
    BH[ks][2] = (_Float16)v0.z; BH[ks][3] = (_Float16)v0.w;
    BH[ks][4] = (_Float16)v1.x; BH[ks][5] = (_Float16)v1.y;
    BH[ks][6] = (_Float16)v1.z; BH[ks][7] = (_Float16)v1.w;
    ssum = fmaf(v0.x, v0.x, ssum); ssum = fmaf(v0.y, v0.y, ssum);
    ssum = fmaf(v0.z, v0.z, ssum); ssum = fmaf(v0.w, v0.w, ssum);
    ssum = fmaf(v1.x, v1.x, ssum); ssum = fmaf(v1.y, v1.y, ssum);
    ssum = fmaf(v1.z, v1.z, ssum); ssum = fmaf(v1.w, v1.w, ssum);
  }
  // lanes {m, m+16, m+32, m+48} hold quarters of row m's norm
  ssum += __shfl_xor(ssum, 16);
  ssum += __shfl_xor(ssum, 32);
  const float b2v = ssum;

#pragma unroll
  for (int j = 0; j < 8; ++j) BN[j] = (_Float16)0.0f;
  if (lg == 0) {
    _Float16 bh = (_Float16)b2v;
    _Float16 bl = (_Float16)(b2v - (float)bh);
    BN[0] = (_Float16)(-1.0f);
    BN[1] = (_Float16)(-1.0f);
    BN[2] = -bh;
    BN[3] = -bl;
    BN[4] = -bh;
  }

  f32x4 pv = {0.f, 0.f, 0.f, 0.f};

  const uint4* xf4 = (const uint4*)xf;
  const uint4* yv4 = (const uint4*)yv;

  uint4 Xa[3], Xb[3], Vp, Vn;
  LOADX3(Xa, n0)
  LOADX3(Xb, n0 + 16)
  Vp = yv4[(size_t)(n0 >> 5) * 64 + lane];

  for (int p = 0; p < npair; ++p) {
    const int nb = n0 + p * 32;
    unsigned UA0, UA1, UB0, UB1;
    SCOMP(Xa, UA0, UA1)
    if (p + 1 < npair) LOADX3(Xa, nb + 32)
    SCOMP(Xb, UB0, UB1)
    if (p + 1 < npair) {
      LOADX3(Xb, nb + 48)
      Vn = yv4[(size_t)((nb + 32) >> 5) * 64 + lane];
    }
    uint4 pa = {UA0, UA1, UB0, UB1};
    pv = mfma_bf32(__builtin_bit_cast(short8, pa),
                   __builtin_bit_cast(short8, Vp), pv);
    Vp = Vn;
  }

  // Epilogue: C[row=m=lg*4+r][col=lr]; col 0 = sum(w), 1..8 = sum(w*y).
  float* pc = partial + (size_t)c * 9 * BATCH;
  if (lr < 9) {
#pragma unroll
    for (int r = 0; r < 4; ++r)
      pc[(size_t)lr * BATCH + (mbase + lg * 4 + r)] = pv[r];
  }
}

// ---------------------------------------------------------------------------
// Pass 2: reduce chunks, divide.
// ---------------------------------------------------------------------------
__global__ __launch_bounds__(256) void grnn_pass2(const float* __restrict__ partial,
                                                  float* __restrict__ out, int nc) {
  int b = blockIdx.x * 256 + threadIdx.x;
  float s1 = 0.f;
  float s2[ODIM];
#pragma unroll
  for (int j = 0; j < ODIM; ++j) s2[j] = 0.f;
  for (int cc = 0; cc < nc; ++cc) {
    const float* p = partial + (size_t)cc * 9 * BATCH;
    s1 += p[b];
#pragma unroll
    for (int j = 0; j < ODIM; ++j) s2[j] += p[(size_t)(j + 1) * BATCH + b];
  }
  const float inv = 1.f / s1;
#pragma unroll
  for (int j = 0; j < ODIM; ++j) out[(size_t)b * ODIM + j] = s2[j] * inv;
}

// ---------------------------------------------------------------------------
extern "C" void kernel_launch(void* const* d_in, const int* in_sizes, int n_in,
                              void* d_out, int out_size, void* d_ws, size_t ws_size,
                              hipStream_t stream) {
  const float* batches = (const float*)d_in[0];  // [8192, 64]
  const float* xt      = (const float*)d_in[1];  // [16384, 64]
  const float* yt      = (const float*)d_in[2];  // [16384, 8]
  const float* beta    = (const float*)d_in[3];  // [1, 16384]
  float* out = (float*)d_out;                    // [8192, 8]

  const size_t xf_b = (size_t)(NTRAIN / 16) * 3 * 1024;    // 3 MB
  const size_t yv_b = (size_t)(NTRAIN / 32) * 64 * 16;     // 512 KB
  const size_t fixed = xf_b + yv_b;
  const size_t per_chunk = (size_t)9 * BATCH * 4;          // 288 KB

  int nc = 32;
  while (nc > 1 && fixed + (size_t)nc * per_chunk > ws_size) nc >>= 1;
  const int chunk_n = NTRAIN / nc;

  char* p = (char*)d_ws;
  u16* xf = (u16*)p;      p += xf_b;
  u16* yv = (u16*)p;      p += yv_b;
  float* partial = (float*)p;

  const int frag_threads = (NTRAIN / 16) * 3 * 64 + (NTRAIN / 32) * 64;
  k_frag<<<(frag_threads + 255) / 256, 256, 0, stream>>>(xt, yt, beta, xf, yv);
  grnn_pass1<<<(BATCH / 64) * nc, 256, 0, stream>>>(
      xf, yv, batches, partial, chunk_n, nc);
  grnn_pass2<<<BATCH / 256, 256, 0, stream>>>(partial, out, nc);
}

// Round 17
// 66.501 us; speedup vs baseline: 1.3180x; 1.3180x over previous
//
#include <hip/hip_runtime.h>
#include <math.h>
#include <stdint.h>

#define NTRAIN 16384
#define DIM 64
#define ODIM 8
#define BATCH 8192
#define LOG2E 1.4426950408889634f

typedef float f32x4 __attribute__((ext_vector_type(4)));
typedef _Float16 f16x8 __attribute__((ext_vector_type(8)));
typedef short short8 __attribute__((ext_vector_type(8)));
typedef unsigned short u16;

// float -> fp16 bits, RNE
static __device__ __forceinline__ u16 f2h(float f) {
  return __builtin_bit_cast(u16, (_Float16)f);
}
static __device__ __forceinline__ float h2f(u16 h) {
  return (float)__builtin_bit_cast(_Float16, h);
}
// float -> bf16 bits, RNE
static __device__ __forceinline__ u16 f2bf(float f) {
  unsigned u = __builtin_bit_cast(unsigned, f);
  u += 0x7FFFu + ((u >> 16) & 1u);
  return (u16)(u >> 16);
}

static __device__ __forceinline__ f32x4 mfma_h32(f16x8 a, f16x8 b, f32x4 c) {
  return __builtin_amdgcn_mfma_f32_16x16x32_f16(a, b, c, 0, 0, 0);
}
static __device__ __forceinline__ f32x4 mfma_bf32(short8 a, short8 b, f32x4 c) {
  return __builtin_amdgcn_mfma_f32_16x16x32_bf16(a, b, c, 0, 0, 0);
}
// 2^(-x)
static __device__ __forceinline__ float ex2n(float x) {
  float r;
  asm("v_exp_f32 %0, -%1" : "=v"(r) : "v"(x));
  return r;
}
// pack two f32 -> one u32 of 2 bf16 (keeps fp32 exponent range)
static __device__ __forceinline__ unsigned pkbf(float a, float b) {
  unsigned d;
  asm("v_cvt_pk_bf16_f32 %0, %1, %2" : "=v"(d) : "v"(a), "v"(b));
  return d;
}

// ---------------------------------------------------------------------------
// k_frag (identical to round 16):
//  X: per 16-n tile, 3 fp16 A-fragments (2 data ksteps of 2*g^2*x + norm kstep)
//  V: per 32-n pair tile, bf16 B-fragment (slab A in k-slots 0..3, B in 4..7)
// ---------------------------------------------------------------------------
__global__ __launch_bounds__(256) void k_frag(
    const float* __restrict__ xt, const float* __restrict__ yt,
    const float* __restrict__ beta,
    u16* __restrict__ xf, u16* __restrict__ yv) {
  int tid = blockIdx.x * 256 + threadIdx.x;

  if (tid < (NTRAIN / 16) * 3 * 64) {
    int fg = tid >> 6, lane = tid & 63;
    int tile = fg / 3, f = fg % 3;
    int lr = lane & 15, lg = lane >> 4;
    int n = tile * 16 + lr;
    uint4 u = {0, 0, 0, 0};
    if (f == 2) {
      if (lg == 0) {
        float g = beta[n] * LOG2E;
        float g2v = g * g;
        const float4* r4 = (const float4*)(xt + (size_t)n * DIM);
        float s0 = 0.f, s1 = 0.f, s2 = 0.f, s3 = 0.f;
#pragma unroll
        for (int q = 0; q < DIM / 4; ++q) {
          float4 v = r4[q];
          s0 = fmaf(v.x, v.x, s0); s1 = fmaf(v.y, v.y, s1);
          s2 = fmaf(v.z, v.z, s2); s3 = fmaf(v.w, v.w, s3);
        }
        float gx2v = g2v * ((s0 + s1) + (s2 + s3));
        u16 xh = f2h(gx2v);
        u16 xl = f2h(gx2v - h2f(xh));
        u16 gh = f2h(g2v);
        u16 gl = f2h(g2v - h2f(gh));
        u.x = (unsigned)xh | ((unsigned)xl << 16);
        u.y = (unsigned)gh | ((unsigned)gh << 16);
        u.z = (unsigned)gl;
      }
    } else {
      float g = beta[n] * LOG2E;
      float s2g = 2.0f * g * g;
      const float* src = xt + (size_t)n * DIM + f * 32 + lg * 8;
      unsigned e[8];
#pragma unroll
      for (int j = 0; j < 8; ++j) e[j] = f2h(s2g * src[j]);
      u.x = e[0] | (e[1] << 16); u.y = e[2] | (e[3] << 16);
      u.z = e[4] | (e[5] << 16); u.w = e[6] | (e[7] << 16);
    }
    ((uint4*)xf)[(size_t)fg * 64 + lane] = u;
    return;
  }
  tid -= (NTRAIN / 16) * 3 * 64;

  if (tid < (NTRAIN / 32) * 64) {  // V pair fragments (bf16)
    int t = tid >> 6, lane = tid & 63;
    int col = lane & 15, lg = lane >> 4;
    unsigned e[8];
#pragma unroll
    for (int j = 0; j < 8; ++j) {
      int n = t * 32 + ((j < 4) ? (lg * 4 + j) : (16 + lg * 4 + (j - 4)));
      float v = (col == 0) ? 1.0f
                           : ((col < 9) ? yt[(size_t)n * ODIM + (col - 1)] : 0.0f);
      e[j] = f2bf(v);
    }
    uint4 u;
    u.x = e[0] | (e[1] << 16); u.y = e[2] | (e[3] << 16);
    u.z = e[4] | (e[5] << 16); u.w = e[6] | (e[7] << 16);
    ((uint4*)yv)[(size_t)t * 64 + lane] = u;
  }
}

// ---------------------------------------------------------------------------
// Pass 1: wave = 32 m-rows (2 x 16-row tiles) -> each X slab read feeds two
// S-tiles, halving L2 traffic vs round 16. fp16 S (3 MFMAs incl norm-fold),
// bf16 P, one 16x16x32 bf16 PV per 2 slabs per tile. Barrier-free;
// register-double-buffered; XCD c-locality swizzle.
// ---------------------------------------------------------------------------
#define LOADX3(X_, nbv)                                                       \
  {                                                                           \
    const size_t fb_ = (size_t)((nbv) >> 4) * 3;                              \
    X_[0] = xf4[(fb_ + 0) * 64 + lane];                                       \
    X_[1] = xf4[(fb_ + 1) * 64 + lane];                                       \
    X_[2] = xf4[(fb_ + 2) * 64 + lane];                                       \
  }

#define SCOMP(X_, BH_, BN_, U0_, U1_)                                         \
  {                                                                           \
    f32x4 sA = {0.f, 0.f, 0.f, 0.f};                                          \
    __builtin_amdgcn_s_setprio(1);                                            \
    sA = mfma_h32(__builtin_bit_cast(f16x8, X_[2]), BN_, sA);                 \
    sA = mfma_h32(__builtin_bit_cast(f16x8, X_[0]), BH_[0], sA);              \
    sA = mfma_h32(__builtin_bit_cast(f16x8, X_[1]), BH_[1], sA);              \
    __builtin_amdgcn_s_setprio(0);                                            \
    float w0 = ex2n(__builtin_amdgcn_sqrtf(fabsf(sA[0])));                    \
    float w1 = ex2n(__builtin_amdgcn_sqrtf(fabsf(sA[1])));                    \
    float w2 = ex2n(__builtin_amdgcn_sqrtf(fabsf(sA[2])));                    \
    float w3 = ex2n(__builtin_amdgcn_sqrtf(fabsf(sA[3])));                    \
    U0_ = pkbf(w0, w1);                                                       \
    U1_ = pkbf(w2, w3);                                                       \
  }

// Build batch fragments for one 16-row tile at mrow_.
#define MAKEB(BH_, BN_, mrow_)                                                \
  {                                                                           \
    float ssum = 0.f;                                                         \
    _Pragma("unroll")                                                         \
    for (int ks = 0; ks < 2; ++ks) {                                          \
      const float* src = batches + (size_t)(mrow_)*DIM + ks * 32 + lg * 8;    \
      float4 v0 = *(const float4*)src;                                        \
      float4 v1 = *(const float4*)(src + 4);                                  \
      BH_[ks][0] = (_Float16)v0.x; BH_[ks][1] = (_Float16)v0.y;               \
      BH_[ks][2] = (_Float16)v0.z; BH_[ks][3] = (_Float16)v0.w;               \
      BH_[ks][4] = (_Float16)v1.x; BH_[ks][5] = (_Float16)v1.y;               \
      BH_[ks][6] = (_Float16)v1.z; BH_[ks][7] = (_Float16)v1.w;               \
      ssum = fmaf(v0.x, v0.x, ssum); ssum = fmaf(v0.y, v0.y, ssum);           \
      ssum = fmaf(v0.z, v0.z, ssum); ssum = fmaf(v0.w, v0.w, ssum);           \
      ssum = fmaf(v1.x, v1.x, ssum); ssum = fmaf(v1.y, v1.y, ssum);           \
      ssum = fmaf(v1.z, v1.z, ssum); ssum = fmaf(v1.w, v1.w, ssum);           \
    }                                                                         \
    ssum += __shfl_xor(ssum, 16);                                             \
    ssum += __shfl_xor(ssum, 32);                                             \
    _Pragma("unroll")                                                         \
    for (int j = 0; j < 8; ++j) BN_[j] = (_Float16)0.0f;                      \
    if (lg == 0) {                                                            \
      _Float16 bh = (_Float16)ssum;                                           \
      _Float16 bl = (_Float16)(ssum - (float)bh);                             \
      BN_[0] = (_Float16)(-1.0f);                                             \
      BN_[1] = (_Float16)(-1.0f);                                             \
      BN_[2] = -bh;                                                           \
      BN_[3] = -bl;                                                           \
      BN_[4] = -bh;                                                           \
    }                                                                         \
  }

__global__ __launch_bounds__(256, 5) void grnn_pass1(
    const u16* __restrict__ xf, const u16* __restrict__ yv,
    const float* __restrict__ batches,
    float* __restrict__ partial, int chunk_n, int nc) {
  const int lane = threadIdx.x & 63;
  const int lr = lane & 15, lg = lane >> 4;

  // XCD c-locality swizzle (bijective for nc==32, grid 2048).
  int mt, c;
  if (nc == 32) {
    const int bid = blockIdx.x;
    const int xcd = bid & 7;
    const int q = bid >> 3;          // 0..255
    c = xcd + 8 * (q & 3);           // 4 c-slices per XCD
    mt = q >> 2;                     // 0..63
  } else {
    mt = blockIdx.x % (BATCH / 128);
    c = blockIdx.x / (BATCH / 128);
  }
  const int mbase = mt * 128 + (threadIdx.x >> 6) * 32;  // wave's 32 m-rows
  const int n0 = c * chunk_n;
  const int npair = chunk_n / 32;

  f16x8 BH0[2], BH1[2], BN0, BN1;
  MAKEB(BH0, BN0, mbase + lr)
  MAKEB(BH1, BN1, mbase + 16 + lr)

  f32x4 pv0 = {0.f, 0.f, 0.f, 0.f};
  f32x4 pv1 = {0.f, 0.f, 0.f, 0.f};

  const uint4* xf4 = (const uint4*)xf;
  const uint4* yv4 = (const uint4*)yv;

  uint4 Xa[3], Xb[3], Vp, Vn;
  LOADX3(Xa, n0)
  LOADX3(Xb, n0 + 16)
  Vp = yv4[(size_t)(n0 >> 5) * 64 + lane];

  for (int p = 0; p < npair; ++p) {
    const int nb = n0 + p * 32;
    unsigned A00, A01, A10, A11, B00, B01, B10, B11;
    SCOMP(Xa, BH0, BN0, A00, A01)   // slab A x tile 0
    SCOMP(Xa, BH1, BN1, A10, A11)   // slab A x tile 1
    if (p + 1 < npair) LOADX3(Xa, nb + 32)
    SCOMP(Xb, BH0, BN0, B00, B01)   // slab B x tile 0
    SCOMP(Xb, BH1, BN1, B10, B11)   // slab B x tile 1
    if (p + 1 < npair) {
      LOADX3(Xb, nb + 48)
      Vn = yv4[(size_t)((nb + 32) >> 5) * 64 + lane];
    }
    uint4 pa0 = {A00, A01, B00, B01};
    uint4 pa1 = {A10, A11, B10, B11};
    pv0 = mfma_bf32(__builtin_bit_cast(short8, pa0),
                    __builtin_bit_cast(short8, Vp), pv0);
    pv1 = mfma_bf32(__builtin_bit_cast(short8, pa1),
                    __builtin_bit_cast(short8, Vp), pv1);
    Vp = Vn;
  }

  // Epilogue: C[row=lg*4+r][col=lr]; col 0 = sum(w), 1..8 = sum(w*y).
  float* pc = partial + (size_t)c * 9 * BATCH;
  if (lr < 9) {
#pragma unroll
    for (int r = 0; r < 4; ++r) {
      pc[(size_t)lr * BATCH + (mbase + lg * 4 + r)] = pv0[r];
      pc[(size_t)lr * BATCH + (mbase + 16 + lg * 4 + r)] = pv1[r];
    }
  }
}

// ---------------------------------------------------------------------------
// Pass 2: reduce chunks, divide.
// ---------------------------------------------------------------------------
__global__ __launch_bounds__(256) void grnn_pass2(const float* __restrict__ partial,
                                                  float* __restrict__ out, int nc) {
  int b = blockIdx.x * 256 + threadIdx.x;
  float s1 = 0.f;
  float s2[ODIM];
#pragma unroll
  for (int j = 0; j < ODIM; ++j) s2[j] = 0.f;
  for (int cc = 0; cc < nc; ++cc) {
    const float* p = partial + (size_t)cc * 9 * BATCH;
    s1 += p[b];
#pragma unroll
    for (int j = 0; j < ODIM; ++j) s2[j] += p[(size_t)(j + 1) * BATCH + b];
  }
  const float inv = 1.f / s1;
#pragma unroll
  for (int j = 0; j < ODIM; ++j) out[(size_t)b * ODIM + j] = s2[j] * inv;
}

// ---------------------------------------------------------------------------
extern "C" void kernel_launch(void* const* d_in, const int* in_sizes, int n_in,
                              void* d_out, int out_size, void* d_ws, size_t ws_size,
                              hipStream_t stream) {
  const float* batches = (const float*)d_in[0];  // [8192, 64]
  const float* xt      = (const float*)d_in[1];  // [16384, 64]
  const float* yt      = (const float*)d_in[2];  // [16384, 8]
  const float* beta    = (const float*)d_in[3];  // [1, 16384]
  float* out = (float*)d_out;                    // [8192, 8]

  const size_t xf_b = (size_t)(NTRAIN / 16) * 3 * 1024;    // 3 MB
  const size_t yv_b = (size_t)(NTRAIN / 32) * 64 * 16;     // 512 KB
  const size_t fixed = xf_b + yv_b;
  const size_t per_chunk = (size_t)9 * BATCH * 4;          // 288 KB

  int nc = 32;
  while (nc > 1 && fixed + (size_t)nc * per_chunk > ws_size) nc >>= 1;
  const int chunk_n = NTRAIN / nc;

  char* p = (char*)d_ws;
  u16* xf = (u16*)p;      p += xf_b;
  u16* yv = (u16*)p;      p += yv_b;
  float* partial = (float*)p;

  const int frag_threads = (NTRAIN / 16) * 3 * 64 + (NTRAIN / 32) * 64;
  k_frag<<<(frag_threads + 255) / 256, 256, 0, stream>>>(xt, yt, beta, xf, yv);
  grnn_pass1<<<(BATCH / 128) * nc, 256, 0, stream>>>(
      xf, yv, batches, partial, chunk_n, nc);
  grnn_pass2<<<BATCH / 256, 256, 0, stream>>>(partial, out, nc);
}

// Round 18
// 65.846 us; speedup vs baseline: 1.3311x; 1.0100x over previous
//
#include <hip/hip_runtime.h>
#include <math.h>
#include <stdint.h>

#define NTRAIN 16384
#define DIM 64
#define ODIM 8
#define BATCH 8192
#define LOG2E 1.4426950408889634f

typedef float f32x4 __attribute__((ext_vector_type(4)));
typedef _Float16 f16x8 __attribute__((ext_vector_type(8)));
typedef short short8 __attribute__((ext_vector_type(8)));
typedef unsigned short u16;

// float -> fp16 bits, RNE
static __device__ __forceinline__ u16 f2h(float f) {
  return __builtin_bit_cast(u16, (_Float16)f);
}
static __device__ __forceinline__ float h2f(u16 h) {
  return (float)__builtin_bit_cast(_Float16, h);
}
// float -> bf16 bits, RNE
static __device__ __forceinline__ u16 f2bf(float f) {
  unsigned u = __builtin_bit_cast(unsigned, f);
  u += 0x7FFFu + ((u >> 16) & 1u);
  return (u16)(u >> 16);
}

static __device__ __forceinline__ f32x4 mfma_h32(f16x8 a, f16x8 b, f32x4 c) {
  return __builtin_amdgcn_mfma_f32_16x16x32_f16(a, b, c, 0, 0, 0);
}
static __device__ __forceinline__ f32x4 mfma_bf32(short8 a, short8 b, f32x4 c) {
  return __builtin_amdgcn_mfma_f32_16x16x32_bf16(a, b, c, 0, 0, 0);
}
// 2^(-x)
static __device__ __forceinline__ float ex2n(float x) {
  float r;
  asm("v_exp_f32 %0, -%1" : "=v"(r) : "v"(x));
  return r;
}
// pack two f32 -> one u32 of 2 bf16 (keeps fp32 exponent range)
static __device__ __forceinline__ unsigned pkbf(float a, float b) {
  unsigned d;
  asm("v_cvt_pk_bf16_f32 %0, %1, %2" : "=v"(d) : "v"(a), "v"(b));
  return d;
}

// ---------------------------------------------------------------------------
// k_frag (identical to rounds 16/17):
//  X: per 16-n tile, 3 fp16 A-fragments (2 data ksteps of 2*g^2*x + norm kstep)
//  V: per 32-n pair tile, bf16 B-fragment (slab A in k-slots 0..3, B in 4..7)
// ---------------------------------------------------------------------------
__global__ __launch_bounds__(256) void k_frag(
    const float* __restrict__ xt, const float* __restrict__ yt,
    const float* __restrict__ beta,
    u16* __restrict__ xf, u16* __restrict__ yv) {
  int tid = blockIdx.x * 256 + threadIdx.x;

  if (tid < (NTRAIN / 16) * 3 * 64) {
    int fg = tid >> 6, lane = tid & 63;
    int tile = fg / 3, f = fg % 3;
    int lr = lane & 15, lg = lane >> 4;
    int n = tile * 16 + lr;
    uint4 u = {0, 0, 0, 0};
    if (f == 2) {
      if (lg == 0) {
        float g = beta[n] * LOG2E;
        float g2v = g * g;
        const float4* r4 = (const float4*)(xt + (size_t)n * DIM);
        float s0 = 0.f, s1 = 0.f, s2 = 0.f, s3 = 0.f;
#pragma unroll
        for (int q = 0; q < DIM / 4; ++q) {
          float4 v = r4[q];
          s0 = fmaf(v.x, v.x, s0); s1 = fmaf(v.y, v.y, s1);
          s2 = fmaf(v.z, v.z, s2); s3 = fmaf(v.w, v.w, s3);
        }
        float gx2v = g2v * ((s0 + s1) + (s2 + s3));
        u16 xh = f2h(gx2v);
        u16 xl = f2h(gx2v - h2f(xh));
        u16 gh = f2h(g2v);
        u16 gl = f2h(g2v - h2f(gh));
        u.x = (unsigned)xh | ((unsigned)xl << 16);
        u.y = (unsigned)gh | ((unsigned)gh << 16);
        u.z = (unsigned)gl;
      }
    } else {
      float g = beta[n] * LOG2E;
      float s2g = 2.0f * g * g;
      const float* src = xt + (size_t)n * DIM + f * 32 + lg * 8;
      unsigned e[8];
#pragma unroll
      for (int j = 0; j < 8; ++j) e[j] = f2h(s2g * src[j]);
      u.x = e[0] | (e[1] << 16); u.y = e[2] | (e[3] << 16);
      u.z = e[4] | (e[5] << 16); u.w = e[6] | (e[7] << 16);
    }
    ((uint4*)xf)[(size_t)fg * 64 + lane] = u;
    return;
  }
  tid -= (NTRAIN / 16) * 3 * 64;

  if (tid < (NTRAIN / 32) * 64) {  // V pair fragments (bf16)
    int t = tid >> 6, lane = tid & 63;
    int col = lane & 15, lg = lane >> 4;
    unsigned e[8];
#pragma unroll
    for (int j = 0; j < 8; ++j) {
      int n = t * 32 + ((j < 4) ? (lg * 4 + j) : (16 + lg * 4 + (j - 4)));
      float v = (col == 0) ? 1.0f
                           : ((col < 9) ? yt[(size_t)n * ODIM + (col - 1)] : 0.0f);
      e[j] = f2bf(v);
    }
    uint4 u;
    u.x = e[0] | (e[1] << 16); u.y = e[2] | (e[3] << 16);
    u.z = e[4] | (e[5] << 16); u.w = e[6] | (e[7] << 16);
    ((uint4*)yv)[(size_t)t * 64 + lane] = u;
  }
}

// ---------------------------------------------------------------------------
// Pass 1: wave = 64 m-rows (4 x 16-row tiles) -> each X slab read feeds FOUR
// S-tiles (L2 traffic ~0.46 GB, under the VALU floor). fp16 S (3 MFMAs incl
// norm-fold), bf16 P, one 16x16x32 bf16 PV per 2 slabs per tile.
// Barrier-free; register-double-buffered; XCD c-locality swizzle.
// ---------------------------------------------------------------------------
#define LOADX3(X_, nbv)                                                       \
  {                                                                           \
    const size_t fb_ = (size_t)((nbv) >> 4) * 3;                              \
    X_[0] = xf4[(fb_ + 0) * 64 + lane];                                       \
    X_[1] = xf4[(fb_ + 1) * 64 + lane];                                       \
    X_[2] = xf4[(fb_ + 2) * 64 + lane];                                       \
  }

#define SCOMP(X_, t_, U0_, U1_)                                               \
  {                                                                           \
    f32x4 sA = {0.f, 0.f, 0.f, 0.f};                                          \
    __builtin_amdgcn_s_setprio(1);                                            \
    sA = mfma_h32(__builtin_bit_cast(f16x8, X_[2]), BN[t_], sA);              \
    sA = mfma_h32(__builtin_bit_cast(f16x8, X_[0]), BH[t_][0], sA);           \
    sA = mfma_h32(__builtin_bit_cast(f16x8, X_[1]), BH[t_][1], sA);           \
    __builtin_amdgcn_s_setprio(0);                                            \
    float w0 = ex2n(__builtin_amdgcn_sqrtf(fabsf(sA[0])));                    \
    float w1 = ex2n(__builtin_amdgcn_sqrtf(fabsf(sA[1])));                    \
    float w2 = ex2n(__builtin_amdgcn_sqrtf(fabsf(sA[2])));                    \
    float w3 = ex2n(__builtin_amdgcn_sqrtf(fabsf(sA[3])));                    \
    U0_ = pkbf(w0, w1);                                                       \
    U1_ = pkbf(w2, w3);                                                       \
  }

__global__ __launch_bounds__(256, 4) void grnn_pass1(
    const u16* __restrict__ xf, const u16* __restrict__ yv,
    const float* __restrict__ batches,
    float* __restrict__ partial, int chunk_n, int nc) {
  const int lane = threadIdx.x & 63;
  const int lr = lane & 15, lg = lane >> 4;

  // XCD c-locality swizzle (bijective for nc==32, grid 1024 = 8*4*32).
  int mt, c;
  if (nc == 32) {
    const int bid = blockIdx.x;
    const int xcd = bid & 7;
    const int q = bid >> 3;          // 0..127
    c = xcd + 8 * (q & 3);           // 4 c-slices per XCD
    mt = q >> 2;                     // 0..31
  } else {
    mt = blockIdx.x % (BATCH / 256);
    c = blockIdx.x / (BATCH / 256);
  }
  const int mbase = mt * 256 + (threadIdx.x >> 6) * 64;  // wave's 64 m-rows
  const int n0 = c * chunk_n;
  const int npair = chunk_n / 32;

  // Batch fragments for 4 m-tiles; b2 via in-wave shfl reduce.
  f16x8 BH[4][2], BN[4];
  f32x4 pv[4];
#pragma unroll
  for (int t = 0; t < 4; ++t) {
    const int mrow = mbase + t * 16 + lr;
    float ssum = 0.f;
#pragma unroll
    for (int ks = 0; ks < 2; ++ks) {
      const float* src = batches + (size_t)mrow * DIM + ks * 32 + lg * 8;
      float4 v0 = *(const float4*)src;
      float4 v1 = *(const float4*)(src + 4);
      BH[t][ks][0] = (_Float16)v0.x; BH[t][ks][1] = (_Float16)v0.y;
      BH[t][ks][2] = (_Float16)v0.z; BH[t][ks][3] = (_Float16)v0.w;
      BH[t][ks][4] = (_Float16)v1.x; BH[t][ks][5] = (_Float16)v1.y;
      BH[t][ks][6] = (_Float16)v1.z; BH[t][ks][7] = (_Float16)v1.w;
      ssum = fmaf(v0.x, v0.x, ssum); ssum = fmaf(v0.y, v0.y, ssum);
      ssum = fmaf(v0.z, v0.z, ssum); ssum = fmaf(v0.w, v0.w, ssum);
      ssum = fmaf(v1.x, v1.x, ssum); ssum = fmaf(v1.y, v1.y, ssum);
      ssum = fmaf(v1.z, v1.z, ssum); ssum = fmaf(v1.w, v1.w, ssum);
    }
    ssum += __shfl_xor(ssum, 16);
    ssum += __shfl_xor(ssum, 32);
#pragma unroll
    for (int j = 0; j < 8; ++j) BN[t][j] = (_Float16)0.0f;
    if (lg == 0) {
      _Float16 bh = (_Float16)ssum;
      _Float16 bl = (_Float16)(ssum - (float)bh);
      BN[t][0] = (_Float16)(-1.0f);
      BN[t][1] = (_Float16)(-1.0f);
      BN[t][2] = -bh;
      BN[t][3] = -bl;
      BN[t][4] = -bh;
    }
    pv[t] = (f32x4){0.f, 0.f, 0.f, 0.f};
  }

  const uint4* xf4 = (const uint4*)xf;
  const uint4* yv4 = (const uint4*)yv;

  uint4 Xa[3], Xb[3], Vp, Vn;
  LOADX3(Xa, n0)
  LOADX3(Xb, n0 + 16)
  Vp = yv4[(size_t)(n0 >> 5) * 64 + lane];

  for (int p = 0; p < npair; ++p) {
    const int nb = n0 + p * 32;
    unsigned A0[4], A1[4], B0[4], B1[4];
#pragma unroll
    for (int t = 0; t < 4; ++t) SCOMP(Xa, t, A0[t], A1[t])
    if (p + 1 < npair) LOADX3(Xa, nb + 32)
#pragma unroll
    for (int t = 0; t < 4; ++t) SCOMP(Xb, t, B0[t], B1[t])
    if (p + 1 < npair) {
      LOADX3(Xb, nb + 48)
      Vn = yv4[(size_t)((nb + 32) >> 5) * 64 + lane];
    }
#pragma unroll
    for (int t = 0; t < 4; ++t) {
      uint4 pa = {A0[t], A1[t], B0[t], B1[t]};
      pv[t] = mfma_bf32(__builtin_bit_cast(short8, pa),
                        __builtin_bit_cast(short8, Vp), pv[t]);
    }
    Vp = Vn;
  }

  // Epilogue: C[row=lg*4+r][col=lr]; col 0 = sum(w), 1..8 = sum(w*y).
  float* pc = partial + (size_t)c * 9 * BATCH;
  if (lr < 9) {
#pragma unroll
    for (int t = 0; t < 4; ++t)
#pragma unroll
      for (int r = 0; r < 4; ++r)
        pc[(size_t)lr * BATCH + (mbase + t * 16 + lg * 4 + r)] = pv[t][r];
  }
}

// ---------------------------------------------------------------------------
// Pass 2: reduce chunks, divide.
// ---------------------------------------------------------------------------
__global__ __launch_bounds__(256) void grnn_pass2(const float* __restrict__ partial,
                                                  float* __restrict__ out, int nc) {
  int b = blockIdx.x * 256 + threadIdx.x;
  float s1 = 0.f;
  float s2[ODIM];
#pragma unroll
  for (int j = 0; j < ODIM; ++j) s2[j] = 0.f;
  for (int cc = 0; cc < nc; ++cc) {
    const float* p = partial + (size_t)cc * 9 * BATCH;
    s1 += p[b];
#pragma unroll
    for (int j = 0; j < ODIM; ++j) s2[j] += p[(size_t)(j + 1) * BATCH + b];
  }
  const float inv = 1.f / s1;
#pragma unroll
  for (int j = 0; j < ODIM; ++j) out[(size_t)b * ODIM + j] = s2[j] * inv;
}

// ---------------------------------------------------------------------------
extern "C" void kernel_launch(void* const* d_in, const int* in_sizes, int n_in,
                              void* d_out, int out_size, void* d_ws, size_t ws_size,
                              hipStream_t stream) {
  const float* batches = (const float*)d_in[0];  // [8192, 64]
  const float* xt      = (const float*)d_in[1];  // [16384, 64]
  const float* yt      = (const float*)d_in[2];  // [16384, 8]
  const float* beta    = (const float*)d_in[3];  // [1, 16384]
  float* out = (float*)d_out;                    // [8192, 8]

  const size_t xf_b = (size_t)(NTRAIN / 16) * 3 * 1024;    // 3 MB
  const size_t yv_b = (size_t)(NTRAIN / 32) * 64 * 16;     // 512 KB
  const size_t fixed = xf_b + yv_b;
  const size_t per_chunk = (size_t)9 * BATCH * 4;          // 288 KB

  int nc = 32;
  while (nc > 1 && fixed + (size_t)nc * per_chunk > ws_size) nc >>= 1;
  const int chunk_n = NTRAIN / nc;

  char* p = (char*)d_ws;
  u16* xf = (u16*)p;      p += xf_b;
  u16* yv = (u16*)p;      p += yv_b;
  float* partial = (float*)p;

  const int frag_threads = (NTRAIN / 16) * 3 * 64 + (NTRAIN / 32) * 64;
  k_frag<<<(frag_threads + 255) / 256, 256, 0, stream>>>(xt, yt, beta, xf, yv);
  grnn_pass1<<<(BATCH / 256) * nc, 256, 0, stream>>>(
      xf, yv, batches, partial, chunk_n, nc);
  grnn_pass2<<<BATCH / 256, 256, 0, stream>>>(partial, out, nc);
}